// Round 3
// baseline (522.468 us; speedup 1.0000x reference)
//
#include <hip/hip_runtime.h>
#include <math.h>

typedef unsigned short ushort_t;
typedef unsigned int uint_t;
typedef short short8 __attribute__((ext_vector_type(8)));
typedef float float4a __attribute__((ext_vector_type(4)));
typedef uint_t uint4a __attribute__((ext_vector_type(4)));
typedef uint_t uint2a __attribute__((ext_vector_type(2)));

#define B_SZ 4
#define S_SZ 2048
#define E_SZ 1024
#define H_SZ 16
#define HD_SZ 64

#if __has_builtin(__builtin_amdgcn_exp2f)
#define EXP2F(x) __builtin_amdgcn_exp2f(x)
#else
#define EXP2F(x) exp2f(x)
#endif

// ---- helpers ----
__device__ __forceinline__ ushort_t f2bf(float f) {
    uint_t u = __builtin_bit_cast(uint_t, f);
    u = (u + 0x7fff + ((u >> 16) & 1)) >> 16;
    return (ushort_t)u;
}
// pack 2 fp32 -> 2 bf16 (round half-up) in one v_perm_b32
__device__ __forceinline__ uint_t pk_bf16(float a, float b) {
    uint_t ua = __builtin_bit_cast(uint_t, a) + 0x8000u;
    uint_t ub = __builtin_bit_cast(uint_t, b) + 0x8000u;
#if __has_builtin(__builtin_amdgcn_perm)
    return __builtin_amdgcn_perm(ub, ua, 0x07060302u);
#else
    return (ua >> 16) | (ub & 0xffff0000u);
#endif
}
__device__ __forceinline__ void async_copy16(const void* g, void* l) {
    __builtin_amdgcn_global_load_lds(
        (const __attribute__((address_space(1))) void*)g,
        (__attribute__((address_space(3))) void*)l, 16, 0, 0);
}

// ---- kernel 1: transpose 4 fp32 weight matrices (E x E) -> bf16 ----
__global__ __launch_bounds__(256) void transpose4(
    const float* __restrict__ W0, const float* __restrict__ W1,
    const float* __restrict__ W2, const float* __restrict__ W3,
    ushort_t* __restrict__ out)
{
    const float* src;
    switch (blockIdx.z) {
        case 0: src = W0; break;
        case 1: src = W1; break;
        case 2: src = W2; break;
        default: src = W3; break;
    }
    ushort_t* dst = out + (size_t)blockIdx.z * (E_SZ * E_SZ);
    __shared__ ushort_t t[32][33];
    int x = blockIdx.x * 32 + threadIdx.x;
    int y0 = blockIdx.y * 32;
    for (int i = threadIdx.y; i < 32; i += 8)
        t[i][threadIdx.x] = f2bf(src[(size_t)(y0 + i) * E_SZ + x]);
    __syncthreads();
    int yy = blockIdx.x * 32;
    int xx = y0 + threadIdx.x;
    for (int i = threadIdx.y; i < 32; i += 8)
        dst[(size_t)(yy + i) * E_SZ + xx] = t[threadIdx.x][i];
}

// ---- kernel 1b: bulk fp32 -> bf16 convert of query/key/value ----
__global__ __launch_bounds__(256) void cvt3(
    const float* __restrict__ s0, const float* __restrict__ s1,
    const float* __restrict__ s2, ushort_t* __restrict__ d0,
    ushort_t* __restrict__ d1, ushort_t* __restrict__ d2)
{
    const float* s; ushort_t* d;
    switch (blockIdx.y) {
        case 0: s = s0; d = d0; break;
        case 1: s = s1; d = d1; break;
        default: s = s2; d = d2; break;
    }
    size_t i = ((size_t)blockIdx.x * 256 + threadIdx.x) * 8;
    float4a u0 = *(const float4a*)(s + i);
    float4a u1 = *(const float4a*)(s + i + 4);
    uint4a w = (uint4a){pk_bf16(u0[0], u0[1]), pk_bf16(u0[2], u0[3]),
                        pk_bf16(u1[0], u1[1]), pk_bf16(u1[2], u1[3])};
    *(uint4a*)(d + i) = w;
}

// ---- GEMM core: Y[m,n] = sum_k X[m,k] * Wt[n,k] + bias[n] ----
// M=8192, N=K=1024.  Round-8: 256x256 tile, BK=32, 512 thr = 8 waves
// (2M x 4N), per-wave C = 128x64 (acc[8][4]).  Rationale (round-2 PMC):
// the 128^2 tile was staging-BW-bound (768 MB total staged at ~16 B/cyc/CU
// => ~2000 cyc per 32 KB K-step, MfmaUtil 11%).  256^2 halves staged
// bytes per MFMA (256 -> 128 B/MFMA => 384 MB total).  K-loop keeps the
// round-2 verified 2-phase schedule verbatim:
//   STAGE(next) -> compute(cur) -> vmcnt(0) -> s_barrier.
// LDS 64 KB: 2 buffers x (A 256x32 + B 256x32) bf16, chunk-major
// [g(4)][row(256)][8] (same zero-bank-conflict pattern as before).
// XCD-aware bijective swizzle: 16 consecutive dispatch-ids per XCD form a
// 4x4 super-tile (X panels 2 MB + W panels 2 MB = 4 MB = one XCD L2).
template<bool OUTF32>
__device__ __forceinline__ void gemm_body(
    const ushort_t* X, const ushort_t* Wt, const float* bias,
    void* Yv, int mode, int tileM, int tileN)
{
    __shared__ __align__(16) ushort_t As[2][8192];   // 16 KB per buffer
    __shared__ __align__(16) ushort_t Bs[2][8192];
    const int tid = threadIdx.x;        // 0..511
    const int lane = tid & 63;
    const int quad = lane >> 4;
    const int l15 = lane & 15;
    const int wid = tid >> 6;           // 0..7
    const int wm = (wid >> 2) * 128;    // wave row-half: 0 / 128
    const int wn = (wid & 3) * 64;      // wave col-quarter: 0/64/128/192

    float4a acc[8][4];
    #pragma unroll
    for (int i = 0; i < 8; i++)
        #pragma unroll
        for (int j = 0; j < 4; j++)
            acc[i][j] = (float4a){0.f, 0.f, 0.f, 0.f};

    // staging addresses: L = p*512 + tid; g = L>>8 (k-chunk), r = L&255 (row)
    // LDS dest L*16B is wave-uniform-base + lane*16 (load_lds requirement).
    const ushort_t* Xa[2];
    const ushort_t* Wa[2];
    int Ld[2];
    #pragma unroll
    for (int p = 0; p < 2; p++) {
        int L = p * 512 + tid;
        int g = L >> 8, r = L & 255;
        Xa[p] = X + (size_t)(tileM + r) * E_SZ + g * 8;
        Wa[p] = Wt + (size_t)(tileN + r) * E_SZ + g * 8;
        Ld[p] = L * 8;
    }

    // prologue: stage K-tile 0 into buffer 0, drain, sync
    #pragma unroll
    for (int p = 0; p < 2; p++) {
        async_copy16(Xa[p], &As[0][Ld[p]]);
        async_copy16(Wa[p], &Bs[0][Ld[p]]);
    }
    asm volatile("s_waitcnt vmcnt(0)" ::: "memory");
    __builtin_amdgcn_s_barrier();
    asm volatile("" ::: "memory");

    for (int kt = 0; kt < 32; kt++) {
        const int cur = kt & 1;
        // issue next tile's staging loads; they fly during the MFMAs below
        if (kt < 31) {
            const int k1 = (kt + 1) * 32;
            #pragma unroll
            for (int p = 0; p < 2; p++) {
                async_copy16(Xa[p] + k1, &As[cur ^ 1][Ld[p]]);
                async_copy16(Wa[p] + k1, &Bs[cur ^ 1][Ld[p]]);
            }
        }
        // compute current tile: 12 ds_read_b128 + 32 MFMA per wave
        short8 a[8], b[4];
        #pragma unroll
        for (int mt = 0; mt < 8; mt++)
            a[mt] = *(const short8*)&As[cur][(quad * 256 + wm + mt * 16 + l15) * 8];
        #pragma unroll
        for (int nt = 0; nt < 4; nt++)
            b[nt] = *(const short8*)&Bs[cur][(quad * 256 + wn + nt * 16 + l15) * 8];
        #pragma unroll
        for (int mt = 0; mt < 8; mt++)
            #pragma unroll
            for (int nt = 0; nt < 4; nt++)
                acc[mt][nt] = __builtin_amdgcn_mfma_f32_16x16x32_bf16(
                    a[mt], b[nt], acc[mt][nt], 0, 0, 0);
        // close staging of next buffer, then sync (one barrier per K-step)
        asm volatile("s_waitcnt vmcnt(0)" ::: "memory");
        __builtin_amdgcn_s_barrier();
        asm volatile("" ::: "memory");
    }

    #pragma unroll
    for (int nt = 0; nt < 4; nt++) {
        int n = tileN + wn + nt * 16 + l15;
        float bv = bias[n];
        #pragma unroll
        for (int mt = 0; mt < 8; mt++) {
            #pragma unroll
            for (int r = 0; r < 4; r++) {
                int m = tileM + wm + mt * 16 + quad * 4 + r;
                float v = acc[mt][nt][r] + bv;
                if constexpr (OUTF32) {
                    ((float*)Yv)[(size_t)m * E_SZ + n] = v;
                } else {
                    ushort_t* Y = (ushort_t*)Yv;
                    if (mode == 0) {
                        Y[(size_t)m * E_SZ + n] = f2bf(v);
                    } else {
                        int bb = m >> 11, s = m & 2047;
                        Y[((size_t)(bb * E_SZ + n)) * S_SZ + s] = f2bf(v);
                    }
                }
            }
        }
    }
}

// bijective XCD swizzle for a 4x32 tile grid (128 blocks, 128%8==0):
// dispatch-id -> (bx, by) such that each XCD gets a 4x4 super-tile chunk.
__device__ __forceinline__ void xcd_swizzle(int* bx, int* by) {
    int id = blockIdx.x + (blockIdx.y << 2);   // 0..127, x fastest = HW order
    int swz = ((id & 7) << 4) + (id >> 3);     // xcd*16 + slot
    *bx = swz & 3;
    *by = swz >> 2;
}

// fused Q/K/V projections: z selects input/weight/bias/output.
__global__ __launch_bounds__(512, 2) void proj3(
    const ushort_t* __restrict__ x0, const ushort_t* __restrict__ x1,
    const ushort_t* __restrict__ x2, const ushort_t* __restrict__ Wt,
    const float* __restrict__ b0, const float* __restrict__ b1,
    const float* __restrict__ b2, ushort_t* __restrict__ y0,
    ushort_t* __restrict__ y1, ushort_t* __restrict__ y2)
{
    const ushort_t* X; const float* bias; ushort_t* Y; int mode = 0;
    switch (blockIdx.z) {
        case 0: X = x0; bias = b0; Y = y0; break;
        case 1: X = x1; bias = b1; Y = y1; break;
        default: X = x2; bias = b2; Y = y2; mode = 1; break;
    }
    int bx, by;
    xcd_swizzle(&bx, &by);
    gemm_body<false>(X, Wt + (size_t)blockIdx.z * E_SZ * E_SZ, bias, Y, mode,
                     by * 256, bx * 256);
}

// final output projection: bf16 X -> fp32 Y
__global__ __launch_bounds__(512, 2) void gemm_out(
    const ushort_t* __restrict__ X, const ushort_t* __restrict__ Wt,
    const float* __restrict__ bias, float* __restrict__ Y)
{
    int bx, by;
    xcd_swizzle(&bx, &by);
    gemm_body<true>(X, Wt, bias, Y, 0, by * 256, bx * 256);
}

// ---- kernel 3: flash attention (round-5 version: online softmax) ----
// Q,K in [B,S,E]. V in [B,E,S] (transposed). Block: 128 q rows per (b,h),
// 4 waves x 32 q rows. S^T = K.Q^T (C-layout row=kidx, col=q); softmax in
// exp2 domain (scale folded into one FMA); P^T packed to bf16 via
// v_perm_b32 and round-tripped through XOR-swizzled LDS; O^T = V^T.P^T.
// NOTE: round-6 fixed-max variant removed the rescale chain but pushed
// VGPR 116->136, crossing the 128-VGPR occupancy step (2->1 blocks/CU,
// 141->252 us). Keep this version's register footprint intact.
__global__ __launch_bounds__(256) void attn(
    const ushort_t* __restrict__ Q, const ushort_t* __restrict__ K,
    const ushort_t* __restrict__ V, ushort_t* __restrict__ ctx)
{
    // PQ: Qs [8][128][8] (8192) at kt==0, then Ps swizzled [128][128]
    __shared__ __align__(16) ushort_t smem[32768];   // 64 KB
    ushort_t* PQ = smem;
    ushort_t* Ks = smem + 16384;         // [g(8)][row(128)][8]
    ushort_t* Vt = smem + 24576;         // swizzled [d(64)][c(128)]

    const int tid = threadIdx.x;
    const int lane = tid & 63;
    const int quad = lane >> 4;
    const int l15 = lane & 15;
    const int wid = tid >> 6;
    const int qt = blockIdx.x;              // 0..15
    const int bh = blockIdx.y;              // 0..63
    const int b = bh >> 4, h = bh & 15;
    const int s0 = qt * 128;
    const int wq = wid * 32;
    const float CE = 0.18033688011f;        // 0.125 * log2(e)

    // stage Q once (completion covered by first in-loop barrier)
    for (int p = 0; p < 4; p++) {
        int L = p * 256 + tid;
        int g = L >> 7, r = L & 127;
        const ushort_t* src = Q + ((size_t)(b * S_SZ + s0 + r)) * E_SZ + h * HD_SZ + g * 8;
        async_copy16(src, &PQ[L * 8]);
    }

    float4a st[8][2];       // S^T acc: mt over kidx(8 x16), nt over q(2 x16)
    float4a o[4][2];        // O^T acc: mt over d(4 x16), nt over q(2 x16)
    for (int mt = 0; mt < 4; mt++)
        for (int nt = 0; nt < 2; nt++)
            o[mt][nt] = (float4a){0.f, 0.f, 0.f, 0.f};
    float mrow[2] = {-1e30f, -1e30f};   // raw-score units
    float lrow[2] = {0.f, 0.f};
    short8 qf[2][2];

    for (int kt = 0; kt < 16; kt++) {
        // stage K tile (async, lane-consecutive 16B)
        for (int p = 0; p < 4; p++) {
            int L = p * 256 + tid;
            int g = L >> 7, r = L & 127;
            const ushort_t* src = K + ((size_t)(b * S_SZ + kt * 128 + r)) * E_SZ + h * HD_SZ + g * 8;
            async_copy16(src, &Ks[L * 8]);
        }
        // stage V^T tile (swizzled rows of 128)
        for (int p = 0; p < 4; p++) {
            int c = p * 256 + tid;
            int d = c >> 4, cc = c & 15;
            const ushort_t* src = V + ((size_t)(b * E_SZ + h * HD_SZ + d)) * S_SZ + kt * 128 + cc * 8;
            short8 val = *(const short8*)src;
            *(short8*)&Vt[d * 128 + ((cc ^ (d & 7)) << 3)] = val;
        }
        __syncthreads();
        if (kt == 0) {
            for (int ks = 0; ks < 2; ks++)
                for (int nt = 0; nt < 2; nt++)
                    qf[ks][nt] = *(const short8*)&PQ[(ks * 4 + quad) * 1024 + (wq + nt * 16 + l15) * 8];
            __syncthreads();   // Ps writes below alias Qs; wait for all qf loads
        }

        // S^T[kidx][q] = sum_d K[kidx][d] * Q[q][d]
        for (int mt = 0; mt < 8; mt++)
            for (int nt = 0; nt < 2; nt++)
                st[mt][nt] = (float4a){0.f, 0.f, 0.f, 0.f};
        for (int ks = 0; ks < 2; ks++) {
            for (int mt = 0; mt < 8; mt++) {
                short8 kf = *(const short8*)&Ks[(ks * 4 + quad) * 1024 + (mt * 16 + l15) * 8];
                for (int nt = 0; nt < 2; nt++)
                    st[mt][nt] = __builtin_amdgcn_mfma_f32_16x16x32_bf16(
                        kf, qf[ks][nt], st[mt][nt], 0, 0, 0);
            }
        }

        // online softmax on raw scores; exp via exp2(st*CE - m*CE)
        float rmax[2] = {-1e30f, -1e30f};
        for (int mt = 0; mt < 8; mt++)
            for (int nt = 0; nt < 2; nt++)
                for (int r = 0; r < 4; r++)
                    rmax[nt] = fmaxf(rmax[nt], st[mt][nt][r]);
        for (int nt = 0; nt < 2; nt++) {
            rmax[nt] = fmaxf(rmax[nt], __shfl_xor(rmax[nt], 16));
            rmax[nt] = fmaxf(rmax[nt], __shfl_xor(rmax[nt], 32));
        }
        float alpha[2], mc[2], rsum[2] = {0.f, 0.f};
        for (int nt = 0; nt < 2; nt++) {
            float mn = fmaxf(mrow[nt], rmax[nt]);
            alpha[nt] = EXP2F((mrow[nt] - mn) * CE);
            mrow[nt] = mn;
            mc[nt] = mn * CE;
        }
        // exp, row-sum, perm-pack to bf16, swizzled LDS write (b64).
        // Each wave touches only its own q rows -> no barrier needed.
        for (int mt = 0; mt < 8; mt++)
            for (int nt = 0; nt < 2; nt++) {
                float e0 = EXP2F(fmaf(st[mt][nt][0], CE, -mc[nt]));
                float e1 = EXP2F(fmaf(st[mt][nt][1], CE, -mc[nt]));
                float e2 = EXP2F(fmaf(st[mt][nt][2], CE, -mc[nt]));
                float e3 = EXP2F(fmaf(st[mt][nt][3], CE, -mc[nt]));
                rsum[nt] += (e0 + e1) + (e2 + e3);
                uint2a pp = (uint2a){pk_bf16(e0, e1), pk_bf16(e2, e3)};
                int row = wq + nt * 16 + l15;
                // element col = mt*16 + quad*4 -> grp = 2mt + (quad>>1)
                *(uint2a*)&PQ[row * 128 + (((2 * mt + (quad >> 1)) ^ (row & 7)) << 3) + (quad & 1) * 4] = pp;
            }
        for (int nt = 0; nt < 2; nt++) {
            rsum[nt] += __shfl_xor(rsum[nt], 16);
            rsum[nt] += __shfl_xor(rsum[nt], 32);
            lrow[nt] = lrow[nt] * alpha[nt] + rsum[nt];
        }
        for (int mt = 0; mt < 4; mt++)
            for (int nt = 0; nt < 2; nt++)
                for (int r = 0; r < 4; r++)
                    o[mt][nt][r] *= alpha[nt];

        // O^T[d][q] += sum_kidx V^T[d][kidx] * P^T[kidx][q]  (16x16x32)
        for (int kk = 0; kk < 4; kk++) {
            int swz = ((kk * 4 + quad) ^ (l15 & 7)) << 3;   // row&7 == l15&7 for all rows used
            short8 a[4], pb[2];
            for (int mt = 0; mt < 4; mt++)
                a[mt] = *(const short8*)&Vt[(mt * 16 + l15) * 128 + swz];
            for (int nt = 0; nt < 2; nt++)
                pb[nt] = *(const short8*)&PQ[(wq + nt * 16 + l15) * 128 + swz];
            for (int mt = 0; mt < 4; mt++)
                for (int nt = 0; nt < 2; nt++)
                    o[mt][nt] = __builtin_amdgcn_mfma_f32_16x16x32_bf16(
                        a[mt], pb[nt], o[mt][nt], 0, 0, 0);
        }
        __syncthreads();
    }

    // epilogue: ctx[b, s, h*64+d] = O^T[d][q] / l[q]   (8B packed stores)
    for (int nt = 0; nt < 2; nt++) {
        float inv = 1.f / lrow[nt];
        int s = s0 + wq + nt * 16 + l15;
        size_t base = ((size_t)(b * S_SZ + s)) * E_SZ + h * HD_SZ;
        for (int mt = 0; mt < 4; mt++) {
            int d = mt * 16 + quad * 4;
            uint2a w = (uint2a){pk_bf16(o[mt][nt][0] * inv, o[mt][nt][1] * inv),
                                pk_bf16(o[mt][nt][2] * inv, o[mt][nt][3] * inv)};
            *(uint2a*)&ctx[base + d] = w;
        }
    }
}

extern "C" void kernel_launch(void* const* d_in, const int* in_sizes, int n_in,
                              void* d_out, int out_size, void* d_ws, size_t ws_size,
                              hipStream_t stream) {
    const float* q_in = (const float*)d_in[0];
    const float* k_in = (const float*)d_in[1];
    const float* v_in = (const float*)d_in[2];
    const float* Wq = (const float*)d_in[3];
    const float* bq = (const float*)d_in[4];
    const float* Wk = (const float*)d_in[5];
    const float* bk = (const float*)d_in[6];
    const float* Wv = (const float*)d_in[7];
    const float* bv = (const float*)d_in[8];
    const float* Wo = (const float*)d_in[9];
    const float* bo = (const float*)d_in[10];

    ushort_t* ws = (ushort_t*)d_ws;
    const size_t WMAT = (size_t)E_SZ * E_SZ;           // 1M elements
    const size_t TEN = (size_t)B_SZ * S_SZ * E_SZ;     // 8M elements
    ushort_t* Wt = ws;                 // 4 transposed bf16 weights (8 MB)
    ushort_t* qb = ws + 4 * WMAT;      // bf16 copies of inputs
    ushort_t* kb = qb + TEN;
    ushort_t* vb = kb + TEN;
    ushort_t* qp = vb + TEN;           // projected Q/K/V
    ushort_t* kp = qp + TEN;
    ushort_t* vp = kp + TEN;           // stored [B, E, S]
    ushort_t* cx = qb;                 // ctx aliases qb (dead after proj3)

    transpose4<<<dim3(32, 32, 4), dim3(32, 8), 0, stream>>>(Wq, Wk, Wv, Wo, Wt);
    cvt3<<<dim3(4096, 3), 256, 0, stream>>>(q_in, k_in, v_in, qb, kb, vb);
    proj3<<<dim3(4, 32, 3), 512, 0, stream>>>(qb, kb, vb, Wt, bq, bk, bv, qp, kp, vp);
    attn<<<dim3(16, 64), 256, 0, stream>>>(qp, kp, vp, cx);
    gemm_out<<<dim3(4, 32), 512, 0, stream>>>(cx, Wt + 3 * WMAT, bo, (float*)d_out);
}

// Round 4
// 458.410 us; speedup vs baseline: 1.1397x; 1.1397x over previous
//
#include <hip/hip_runtime.h>
#include <math.h>

typedef unsigned short ushort_t;
typedef unsigned int uint_t;
typedef short short8 __attribute__((ext_vector_type(8)));
typedef float float4a __attribute__((ext_vector_type(4)));
typedef uint_t uint4a __attribute__((ext_vector_type(4)));
typedef uint_t uint2a __attribute__((ext_vector_type(2)));

#define B_SZ 4
#define S_SZ 2048
#define E_SZ 1024
#define H_SZ 16
#define HD_SZ 64

#if __has_builtin(__builtin_amdgcn_exp2f)
#define EXP2F(x) __builtin_amdgcn_exp2f(x)
#else
#define EXP2F(x) exp2f(x)
#endif

// ---- helpers ----
__device__ __forceinline__ ushort_t f2bf(float f) {
    uint_t u = __builtin_bit_cast(uint_t, f);
    u = (u + 0x7fff + ((u >> 16) & 1)) >> 16;
    return (ushort_t)u;
}
// pack 2 fp32 -> 2 bf16 (round half-up) in one v_perm_b32
__device__ __forceinline__ uint_t pk_bf16(float a, float b) {
    uint_t ua = __builtin_bit_cast(uint_t, a) + 0x8000u;
    uint_t ub = __builtin_bit_cast(uint_t, b) + 0x8000u;
#if __has_builtin(__builtin_amdgcn_perm)
    return __builtin_amdgcn_perm(ub, ua, 0x07060302u);
#else
    return (ua >> 16) | (ub & 0xffff0000u);
#endif
}
__device__ __forceinline__ void async_copy16(const void* g, void* l) {
    __builtin_amdgcn_global_load_lds(
        (const __attribute__((address_space(1))) void*)g,
        (__attribute__((address_space(3))) void*)l, 16, 0, 0);
}

// ---- kernel 1: transpose 4 fp32 weight matrices (E x E) -> bf16 ----
__global__ __launch_bounds__(256) void transpose4(
    const float* __restrict__ W0, const float* __restrict__ W1,
    const float* __restrict__ W2, const float* __restrict__ W3,
    ushort_t* __restrict__ out)
{
    const float* src;
    switch (blockIdx.z) {
        case 0: src = W0; break;
        case 1: src = W1; break;
        case 2: src = W2; break;
        default: src = W3; break;
    }
    ushort_t* dst = out + (size_t)blockIdx.z * (E_SZ * E_SZ);
    __shared__ ushort_t t[32][33];
    int x = blockIdx.x * 32 + threadIdx.x;
    int y0 = blockIdx.y * 32;
    for (int i = threadIdx.y; i < 32; i += 8)
        t[i][threadIdx.x] = f2bf(src[(size_t)(y0 + i) * E_SZ + x]);
    __syncthreads();
    int yy = blockIdx.x * 32;
    int xx = y0 + threadIdx.x;
    for (int i = threadIdx.y; i < 32; i += 8)
        dst[(size_t)(yy + i) * E_SZ + xx] = t[threadIdx.x][i];
}

// ---- kernel 1b: bulk fp32 -> bf16 convert of query/key/value ----
__global__ __launch_bounds__(256) void cvt3(
    const float* __restrict__ s0, const float* __restrict__ s1,
    const float* __restrict__ s2, ushort_t* __restrict__ d0,
    ushort_t* __restrict__ d1, ushort_t* __restrict__ d2)
{
    const float* s; ushort_t* d;
    switch (blockIdx.y) {
        case 0: s = s0; d = d0; break;
        case 1: s = s1; d = d1; break;
        default: s = s2; d = d2; break;
    }
    size_t i = ((size_t)blockIdx.x * 256 + threadIdx.x) * 8;
    float4a u0 = *(const float4a*)(s + i);
    float4a u1 = *(const float4a*)(s + i + 4);
    uint4a w = (uint4a){pk_bf16(u0[0], u0[1]), pk_bf16(u0[2], u0[3]),
                        pk_bf16(u1[0], u1[1]), pk_bf16(u1[2], u1[3])};
    *(uint4a*)(d + i) = w;
}

// ---- GEMM core: Y[m,n] = sum_k X[m,k] * Wt[n,k] + bias[n] ----
// M=8192, N=K=1024.  Round-9: 128x128 tile (round-0 proven geometry),
// BK=32, 4-slot LDS ring (4 x 16 KB = 64 KB -> still 2 blocks/CU) with
// COUNTED vmcnt: prefetch runs 3 K-steps ahead; steady state waits only
// vmcnt(12) (16 loads in flight, oldest 4 = tile j), issued ~2000 cyc
// earlier -> no per-step latency drain.  Rationale: rounds 0/2/3 all
// pinned at 150-186 us with MfmaUtil 11-14% regardless of tile size or
// traffic (FETCH 200 vs 49 MB, same dur) => per-step vmcnt(0) drain
// (~900 cyc) serializing against ~620 cyc of MFMA is the bound.  Counted
// vmcnt is the one measured fix (T4: +38-73%; AITER never waits to 0).
// Race audit: stage at step j writes slot (j+3)&3 == (j-1)&3, whose
// reads were closed by the lgkmcnt(0)+barrier at step j's top; barrier
// after vmcnt(12) publishes tile j's LDS before any wave reads it.
template<bool OUTF32>
__device__ __forceinline__ void gemm_body(
    const ushort_t* X, const ushort_t* Wt, const float* bias,
    void* Yv, int mode, int tileM, int tileN)
{
    __shared__ __align__(16) ushort_t As[4][4096];   // 8 KB per slot
    __shared__ __align__(16) ushort_t Bs[4][4096];   // 8 KB per slot
    const int tid = threadIdx.x;
    const int lane = tid & 63;
    const int quad = lane >> 4;
    const int l15 = lane & 15;
    const int wid = tid >> 6;
    const int wm = (wid >> 1) * 64;
    const int wn = (wid & 1) * 64;

    float4a acc[4][4];
    #pragma unroll
    for (int i = 0; i < 4; i++)
        #pragma unroll
        for (int j = 0; j < 4; j++)
            acc[i][j] = (float4a){0.f, 0.f, 0.f, 0.f};

    // staging: per step each thread issues 2 A-loads + 2 B-loads (16B).
    // L = p*256 + tid; g = L>>7 (k-chunk of 8), r = L&127 (row).
    // LDS dest = slot base + L*16B (linear in L: load_lds requirement).
    const ushort_t* pA0 = X  + (size_t)(tileM + (tid & 127)) * E_SZ + (tid >> 7) * 8;
    const ushort_t* pA1 = X  + (size_t)(tileM + (tid & 127)) * E_SZ + ((tid >> 7) + 2) * 8;
    const ushort_t* pB0 = Wt + (size_t)(tileN + (tid & 127)) * E_SZ + (tid >> 7) * 8;
    const ushort_t* pB1 = Wt + (size_t)(tileN + (tid & 127)) * E_SZ + ((tid >> 7) + 2) * 8;
    const int d0 = tid * 8;            // elements; L=tid
    const int d1 = (256 + tid) * 8;    // L=256+tid

#define STAGE(SLOT) do { \
    async_copy16(pA0, &As[SLOT][d0]); \
    async_copy16(pA1, &As[SLOT][d1]); \
    async_copy16(pB0, &Bs[SLOT][d0]); \
    async_copy16(pB1, &Bs[SLOT][d1]); \
    pA0 += 32; pA1 += 32; pB0 += 32; pB1 += 32; } while (0)

    // prologue: stage K-steps 0,1,2 into slots 0,1,2 (12 loads in flight)
    STAGE(0); STAGE(1); STAGE(2);

// One K-step: close prev reads (lgkm+barrier) so staging may overwrite
// slot (j-1); issue prefetch j+3; counted wait for tile j; barrier; then
// 8 ds_read_b128 + 16 MFMA.
#define KTILE(SLOT, DOSTAGE, VMS) do { \
    asm volatile("s_waitcnt lgkmcnt(0)" ::: "memory"); \
    __builtin_amdgcn_s_barrier(); \
    asm volatile("" ::: "memory"); \
    if (DOSTAGE) STAGE(((SLOT) + 3) & 3); \
    asm volatile("s_waitcnt vmcnt(" #VMS ")" ::: "memory"); \
    __builtin_amdgcn_s_barrier(); \
    asm volatile("" ::: "memory"); \
    { \
        short8 a[4], b[4]; \
        _Pragma("unroll") \
        for (int mt = 0; mt < 4; mt++) \
            a[mt] = *(const short8*)&As[SLOT][quad * 1024 + (wm + mt * 16 + l15) * 8]; \
        _Pragma("unroll") \
        for (int nt = 0; nt < 4; nt++) \
            b[nt] = *(const short8*)&Bs[SLOT][quad * 1024 + (wn + nt * 16 + l15) * 8]; \
        __builtin_amdgcn_s_setprio(1); \
        _Pragma("unroll") \
        for (int mt = 0; mt < 4; mt++) \
            _Pragma("unroll") \
            for (int nt = 0; nt < 4; nt++) \
                acc[mt][nt] = __builtin_amdgcn_mfma_f32_16x16x32_bf16( \
                    a[mt], b[nt], acc[mt][nt], 0, 0, 0); \
        __builtin_amdgcn_s_setprio(0); \
    } } while (0)

    #pragma unroll 1
    for (int j = 0; j < 28; j += 4) {
        KTILE(0, true, 12);
        KTILE(1, true, 12);
        KTILE(2, true, 12);
        KTILE(3, true, 12);
    }
    KTILE(0, true, 12);    // j=28: stages K-step 31 -> slot 3
    KTILE(1, false, 8);    // j=29: tiles 30,31 in flight
    KTILE(2, false, 4);    // j=30
    KTILE(3, false, 0);    // j=31
#undef KTILE
#undef STAGE

    #pragma unroll
    for (int nt = 0; nt < 4; nt++) {
        int n = tileN + wn + nt * 16 + l15;
        float bv = bias[n];
        #pragma unroll
        for (int mt = 0; mt < 4; mt++) {
            #pragma unroll
            for (int r = 0; r < 4; r++) {
                int m = tileM + wm + mt * 16 + quad * 4 + r;
                float v = acc[mt][nt][r] + bv;
                if constexpr (OUTF32) {
                    ((float*)Yv)[(size_t)m * E_SZ + n] = v;
                } else {
                    ushort_t* Y = (ushort_t*)Yv;
                    if (mode == 0) {
                        Y[(size_t)m * E_SZ + n] = f2bf(v);
                    } else {
                        int bb = m >> 11, s = m & 2047;
                        Y[((size_t)(bb * E_SZ + n)) * S_SZ + s] = f2bf(v);
                    }
                }
            }
        }
    }
}

// fused Q/K/V projections: z selects input/weight/bias/output.
__global__ __launch_bounds__(256, 2) void proj3(
    const ushort_t* __restrict__ x0, const ushort_t* __restrict__ x1,
    const ushort_t* __restrict__ x2, const ushort_t* __restrict__ Wt,
    const float* __restrict__ b0, const float* __restrict__ b1,
    const float* __restrict__ b2, ushort_t* __restrict__ y0,
    ushort_t* __restrict__ y1, ushort_t* __restrict__ y2)
{
    const ushort_t* X; const float* bias; ushort_t* Y; int mode = 0;
    switch (blockIdx.z) {
        case 0: X = x0; bias = b0; Y = y0; break;
        case 1: X = x1; bias = b1; Y = y1; break;
        default: X = x2; bias = b2; Y = y2; mode = 1; break;
    }
    gemm_body<false>(X, Wt + (size_t)blockIdx.z * E_SZ * E_SZ, bias, Y, mode,
                     blockIdx.y * 128, blockIdx.x * 128);
}

// final output projection: bf16 X -> fp32 Y
__global__ __launch_bounds__(256, 2) void gemm_out(
    const ushort_t* __restrict__ X, const ushort_t* __restrict__ Wt,
    const float* __restrict__ bias, float* __restrict__ Y)
{
    gemm_body<true>(X, Wt, bias, Y, 0, blockIdx.y * 128, blockIdx.x * 128);
}

// ---- kernel 3: flash attention (round-5 version: online softmax) ----
// Q,K in [B,S,E]. V in [B,E,S] (transposed). Block: 128 q rows per (b,h),
// 4 waves x 32 q rows. S^T = K.Q^T (C-layout row=kidx, col=q); softmax in
// exp2 domain (scale folded into one FMA); P^T packed to bf16 via
// v_perm_b32 and round-tripped through XOR-swizzled LDS; O^T = V^T.P^T.
// NOTE: round-6 fixed-max variant removed the rescale chain but pushed
// VGPR 116->136, crossing the 128-VGPR occupancy step (2->1 blocks/CU,
// 141->252 us). Keep this version's register footprint intact.
__global__ __launch_bounds__(256) void attn(
    const ushort_t* __restrict__ Q, const ushort_t* __restrict__ K,
    const ushort_t* __restrict__ V, ushort_t* __restrict__ ctx)
{
    // PQ: Qs [8][128][8] (8192) at kt==0, then Ps swizzled [128][128]
    __shared__ __align__(16) ushort_t smem[32768];   // 64 KB
    ushort_t* PQ = smem;
    ushort_t* Ks = smem + 16384;         // [g(8)][row(128)][8]
    ushort_t* Vt = smem + 24576;         // swizzled [d(64)][c(128)]

    const int tid = threadIdx.x;
    const int lane = tid & 63;
    const int quad = lane >> 4;
    const int l15 = lane & 15;
    const int wid = tid >> 6;
    const int qt = blockIdx.x;              // 0..15
    const int bh = blockIdx.y;              // 0..63
    const int b = bh >> 4, h = bh & 15;
    const int s0 = qt * 128;
    const int wq = wid * 32;
    const float CE = 0.18033688011f;        // 0.125 * log2(e)

    // stage Q once (completion covered by first in-loop barrier)
    for (int p = 0; p < 4; p++) {
        int L = p * 256 + tid;
        int g = L >> 7, r = L & 127;
        const ushort_t* src = Q + ((size_t)(b * S_SZ + s0 + r)) * E_SZ + h * HD_SZ + g * 8;
        async_copy16(src, &PQ[L * 8]);
    }

    float4a st[8][2];       // S^T acc: mt over kidx(8 x16), nt over q(2 x16)
    float4a o[4][2];        // O^T acc: mt over d(4 x16), nt over q(2 x16)
    for (int mt = 0; mt < 4; mt++)
        for (int nt = 0; nt < 2; nt++)
            o[mt][nt] = (float4a){0.f, 0.f, 0.f, 0.f};
    float mrow[2] = {-1e30f, -1e30f};   // raw-score units
    float lrow[2] = {0.f, 0.f};
    short8 qf[2][2];

    for (int kt = 0; kt < 16; kt++) {
        // stage K tile (async, lane-consecutive 16B)
        for (int p = 0; p < 4; p++) {
            int L = p * 256 + tid;
            int g = L >> 7, r = L & 127;
            const ushort_t* src = K + ((size_t)(b * S_SZ + kt * 128 + r)) * E_SZ + h * HD_SZ + g * 8;
            async_copy16(src, &Ks[L * 8]);
        }
        // stage V^T tile (swizzled rows of 128)
        for (int p = 0; p < 4; p++) {
            int c = p * 256 + tid;
            int d = c >> 4, cc = c & 15;
            const ushort_t* src = V + ((size_t)(b * E_SZ + h * HD_SZ + d)) * S_SZ + kt * 128 + cc * 8;
            short8 val = *(const short8*)src;
            *(short8*)&Vt[d * 128 + ((cc ^ (d & 7)) << 3)] = val;
        }
        __syncthreads();
        if (kt == 0) {
            for (int ks = 0; ks < 2; ks++)
                for (int nt = 0; nt < 2; nt++)
                    qf[ks][nt] = *(const short8*)&PQ[(ks * 4 + quad) * 1024 + (wq + nt * 16 + l15) * 8];
            __syncthreads();   // Ps writes below alias Qs; wait for all qf loads
        }

        // S^T[kidx][q] = sum_d K[kidx][d] * Q[q][d]
        for (int mt = 0; mt < 8; mt++)
            for (int nt = 0; nt < 2; nt++)
                st[mt][nt] = (float4a){0.f, 0.f, 0.f, 0.f};
        for (int ks = 0; ks < 2; ks++) {
            for (int mt = 0; mt < 8; mt++) {
                short8 kf = *(const short8*)&Ks[(ks * 4 + quad) * 1024 + (mt * 16 + l15) * 8];
                for (int nt = 0; nt < 2; nt++)
                    st[mt][nt] = __builtin_amdgcn_mfma_f32_16x16x32_bf16(
                        kf, qf[ks][nt], st[mt][nt], 0, 0, 0);
            }
        }

        // online softmax on raw scores; exp via exp2(st*CE - m*CE)
        float rmax[2] = {-1e30f, -1e30f};
        for (int mt = 0; mt < 8; mt++)
            for (int nt = 0; nt < 2; nt++)
                for (int r = 0; r < 4; r++)
                    rmax[nt] = fmaxf(rmax[nt], st[mt][nt][r]);
        for (int nt = 0; nt < 2; nt++) {
            rmax[nt] = fmaxf(rmax[nt], __shfl_xor(rmax[nt], 16));
            rmax[nt] = fmaxf(rmax[nt], __shfl_xor(rmax[nt], 32));
        }
        float alpha[2], mc[2], rsum[2] = {0.f, 0.f};
        for (int nt = 0; nt < 2; nt++) {
            float mn = fmaxf(mrow[nt], rmax[nt]);
            alpha[nt] = EXP2F((mrow[nt] - mn) * CE);
            mrow[nt] = mn;
            mc[nt] = mn * CE;
        }
        // exp, row-sum, perm-pack to bf16, swizzled LDS write (b64).
        // Each wave touches only its own q rows -> no barrier needed.
        for (int mt = 0; mt < 8; mt++)
            for (int nt = 0; nt < 2; nt++) {
                float e0 = EXP2F(fmaf(st[mt][nt][0], CE, -mc[nt]));
                float e1 = EXP2F(fmaf(st[mt][nt][1], CE, -mc[nt]));
                float e2 = EXP2F(fmaf(st[mt][nt][2], CE, -mc[nt]));
                float e3 = EXP2F(fmaf(st[mt][nt][3], CE, -mc[nt]));
                rsum[nt] += (e0 + e1) + (e2 + e3);
                uint2a pp = (uint2a){pk_bf16(e0, e1), pk_bf16(e2, e3)};
                int row = wq + nt * 16 + l15;
                // element col = mt*16 + quad*4 -> grp = 2mt + (quad>>1)
                *(uint2a*)&PQ[row * 128 + (((2 * mt + (quad >> 1)) ^ (row & 7)) << 3) + (quad & 1) * 4] = pp;
            }
        for (int nt = 0; nt < 2; nt++) {
            rsum[nt] += __shfl_xor(rsum[nt], 16);
            rsum[nt] += __shfl_xor(rsum[nt], 32);
            lrow[nt] = lrow[nt] * alpha[nt] + rsum[nt];
        }
        for (int mt = 0; mt < 4; mt++)
            for (int nt = 0; nt < 2; nt++)
                for (int r = 0; r < 4; r++)
                    o[mt][nt][r] *= alpha[nt];

        // O^T[d][q] += sum_kidx V^T[d][kidx] * P^T[kidx][q]  (16x16x32)
        for (int kk = 0; kk < 4; kk++) {
            int swz = ((kk * 4 + quad) ^ (l15 & 7)) << 3;   // row&7 == l15&7 for all rows used
            short8 a[4], pb[2];
            for (int mt = 0; mt < 4; mt++)
                a[mt] = *(const short8*)&Vt[(mt * 16 + l15) * 128 + swz];
            for (int nt = 0; nt < 2; nt++)
                pb[nt] = *(const short8*)&PQ[(wq + nt * 16 + l15) * 128 + swz];
            for (int mt = 0; mt < 4; mt++)
                for (int nt = 0; nt < 2; nt++)
                    o[mt][nt] = __builtin_amdgcn_mfma_f32_16x16x32_bf16(
                        a[mt], pb[nt], o[mt][nt], 0, 0, 0);
        }
        __syncthreads();
    }

    // epilogue: ctx[b, s, h*64+d] = O^T[d][q] / l[q]   (8B packed stores)
    for (int nt = 0; nt < 2; nt++) {
        float inv = 1.f / lrow[nt];
        int s = s0 + wq + nt * 16 + l15;
        size_t base = ((size_t)(b * S_SZ + s)) * E_SZ + h * HD_SZ;
        for (int mt = 0; mt < 4; mt++) {
            int d = mt * 16 + quad * 4;
            uint2a w = (uint2a){pk_bf16(o[mt][nt][0] * inv, o[mt][nt][1] * inv),
                                pk_bf16(o[mt][nt][2] * inv, o[mt][nt][3] * inv)};
            *(uint2a*)&ctx[base + d] = w;
        }
    }
}

extern "C" void kernel_launch(void* const* d_in, const int* in_sizes, int n_in,
                              void* d_out, int out_size, void* d_ws, size_t ws_size,
                              hipStream_t stream) {
    const float* q_in = (const float*)d_in[0];
    const float* k_in = (const float*)d_in[1];
    const float* v_in = (const float*)d_in[2];
    const float* Wq = (const float*)d_in[3];
    const float* bq = (const float*)d_in[4];
    const float* Wk = (const float*)d_in[5];
    const float* bk = (const float*)d_in[6];
    const float* Wv = (const float*)d_in[7];
    const float* bv = (const float*)d_in[8];
    const float* Wo = (const float*)d_in[9];
    const float* bo = (const float*)d_in[10];

    ushort_t* ws = (ushort_t*)d_ws;
    const size_t WMAT = (size_t)E_SZ * E_SZ;           // 1M elements
    const size_t TEN = (size_t)B_SZ * S_SZ * E_SZ;     // 8M elements
    ushort_t* Wt = ws;                 // 4 transposed bf16 weights (8 MB)
    ushort_t* qb = ws + 4 * WMAT;      // bf16 copies of inputs
    ushort_t* kb = qb + TEN;
    ushort_t* vb = kb + TEN;
    ushort_t* qp = vb + TEN;           // projected Q/K/V
    ushort_t* kp = qp + TEN;
    ushort_t* vp = kp + TEN;           // stored [B, E, S]
    ushort_t* cx = qb;                 // ctx aliases qb (dead after proj3)

    transpose4<<<dim3(32, 32, 4), dim3(32, 8), 0, stream>>>(Wq, Wk, Wv, Wo, Wt);
    cvt3<<<dim3(4096, 3), 256, 0, stream>>>(q_in, k_in, v_in, qb, kb, vb);
    proj3<<<dim3(8, 64, 3), 256, 0, stream>>>(qb, kb, vb, Wt, bq, bk, bv, qp, kp, vp);
    attn<<<dim3(16, 64), 256, 0, stream>>>(qp, kp, vp, cx);
    gemm_out<<<dim3(8, 64), 256, 0, stream>>>(cx, Wt + 3 * WMAT, bo, (float*)d_out);
}